// Round 1
// baseline (347.004 us; speedup 1.0000x reference)
//
#include <hip/hip_runtime.h>
#include <hip/hip_bf16.h>

typedef int   int4v   __attribute__((ext_vector_type(4)));
typedef float float4v __attribute__((ext_vector_type(4)));

#define T_TOK 16384
#define TPAD  16448     // T + 64 pad so ragged GEMM tiles can over-read safely
#define HD    1024
#define IE    256
#define EN    8
#define VSZ   100000

// meta[] int indices
#define M_CNT 0    // [8] histogram
#define M_CUR 8    // [8] cursors
#define M_OFF 16   // [9] group offsets
#define M_TS1 25   // [9] gemm1 tile-start prefix (Mtile=64)
#define M_TS2 34   // [9] gemm2 tile-start prefix (Mtile=32)

// ws byte offsets (all 16-aligned)
#define XQ_OFF   0ull           // TPAD*1024 int8
#define IQ_OFF   16842752ull    // TPAD*256 int8
#define PB1_OFF  21053440ull    // 8*64*512*16 int8 (gate|up packed)
#define PB2_OFF  25247744ull    // 8*16*1024*16 int8 (down packed)
#define PERM_OFF 27344896ull    // TPAD int32
#define XS_OFF   27410688ull    // TPAD float
#define IS_OFF   27476480ull    // TPAD float
#define META_OFF 27542272ull    // 64 int32

__global__ void k_init(int* meta) {
    if (threadIdx.x < 64) meta[threadIdx.x] = 0;
}

__global__ void k_hist(const int* __restrict__ ids, const int* __restrict__ t2e, int* meta) {
    __shared__ int h[EN];
    int tid = threadIdx.x;
    if (tid < EN) h[tid] = 0;
    __syncthreads();
    int t = blockIdx.x * 256 + tid;
    int id = ids[t]; id = min(max(id, 0), VSZ - 1);
    atomicAdd(&h[t2e[id]], 1);
    __syncthreads();
    if (tid < EN) atomicAdd(&meta[M_CNT + tid], h[tid]);
}

__global__ void k_offsets(int* meta) {
    int off = 0, t1 = 0, t2 = 0;
    meta[M_OFF] = 0; meta[M_TS1] = 0; meta[M_TS2] = 0;
    for (int e = 0; e < EN; ++e) {
        int c = meta[M_CNT + e];
        off += c; t1 += (c + 63) >> 6; t2 += (c + 31) >> 5;
        meta[M_OFF + e + 1] = off;
        meta[M_TS1 + e + 1] = t1;
        meta[M_TS2 + e + 1] = t2;
    }
}

__global__ void k_assign(const int* __restrict__ ids, const int* __restrict__ t2e,
                         int* meta, int* __restrict__ perm) {
    int t = blockIdx.x * 256 + threadIdx.x;
    int id = ids[t]; id = min(max(id, 0), VSZ - 1);
    int e = t2e[id];
    int slot = meta[M_OFF + e] + atomicAdd(&meta[M_CUR + e], 1);
    perm[slot] = t;
}

// int32-weights -> int8 packed fragment layout: elem(k,n) at ((k>>4)*N + n)*16 + (k&15)
__global__ __launch_bounds__(256) void k_repack(const int* __restrict__ gq,
                                                const int* __restrict__ uq,
                                                const int* __restrict__ dq,
                                                signed char* __restrict__ pb1,
                                                signed char* __restrict__ pb2) {
    int idx = blockIdx.x * 256 + threadIdx.x;   // 0 .. 6291455
    if (idx < 4194304) {                        // gate|up: [8][1024][512]
        int n = idx & 511, k = (idx >> 9) & 1023, e = idx >> 19;
        int v = (n < 256) ? gq[(((e << 10) + k) << 8) + n]
                          : uq[(((e << 10) + k) << 8) + (n - 256)];
        pb1[(size_t)(((((e << 6) + (k >> 4)) << 9) + n) << 4) + (k & 15)] = (signed char)v;
    } else {                                    // down: [8][256][1024]
        int j = idx - 4194304;
        int n = j & 1023, k = (j >> 10) & 255, e = j >> 18;
        int v = dq[(((e << 8) + k) << 10) + n];
        pb2[(size_t)(((((e << 4) + (k >> 4)) << 10) + n) << 4) + (k & 15)] = (signed char)v;
    }
}

// one wave per slot: gather token row, rowwise int8 quantize (bit-exact vs ref)
__global__ __launch_bounds__(256) void k_quant(const float* __restrict__ hidden,
                                               const int* __restrict__ perm,
                                               signed char* __restrict__ xq,
                                               float* __restrict__ xs) {
    int w = threadIdx.x >> 6, lane = threadIdx.x & 63;
    int slot = blockIdx.x * 4 + w;
    int token = perm[slot];
    const float* row = hidden + (size_t)token * HD;
    float v[16];
    #pragma unroll
    for (int j = 0; j < 4; ++j) {
        float4v f = *(const float4v*)(row + lane * 16 + j * 4);
        v[j*4+0] = f[0]; v[j*4+1] = f[1]; v[j*4+2] = f[2]; v[j*4+3] = f[3];
    }
    float mx = 0.0f;
    #pragma unroll
    for (int j = 0; j < 16; ++j) mx = fmaxf(mx, fabsf(v[j]));
    #pragma unroll
    for (int s = 1; s < 64; s <<= 1) mx = fmaxf(mx, __shfl_xor(mx, s, 64));
    float sc = fmaxf(mx / 127.0f, 1e-8f);
    if (lane == 0) xs[slot] = sc;
    int4v pk;
    #pragma unroll
    for (int j = 0; j < 4; ++j) {
        int b[4];
        #pragma unroll
        for (int u = 0; u < 4; ++u) {
            float t = rintf(v[j*4+u] / sc);           // round-half-even == jnp.round
            t = fminf(fmaxf(t, -128.0f), 127.0f);
            b[u] = (int)t;
        }
        pk[j] = (b[0] & 255) | ((b[1] & 255) << 8) | ((b[2] & 255) << 16) | (b[3] << 24);
    }
    *(int4v*)(xq + (size_t)slot * HD + lane * 16) = pk;
}

// GEMM1: per block Mtile=64, N=512 (gate 0..255 | up 256..511), K=1024.
// wave w owns gate cols [w*64,w*64+64) and matching up cols. Epilogue: silu*up,
// rowwise requantize (cross-wave max via LDS), write Iq int8 + i_s.
__global__ __launch_bounds__(256) void k_gemm1(const signed char* __restrict__ xq,
                                               const signed char* __restrict__ pb1,
                                               const float* __restrict__ xs,
                                               const float* __restrict__ gsc,
                                               const float* __restrict__ usc,
                                               const int* __restrict__ meta,
                                               signed char* __restrict__ iq,
                                               float* __restrict__ isc) {
    int b = blockIdx.x;
    int e = -1, m0 = 0, gend = 0;
    #pragma unroll
    for (int i = 0; i < EN; ++i) {
        int s0 = meta[M_TS1 + i], s1 = meta[M_TS1 + i + 1];
        if (b >= s0 && b < s1) { e = i; m0 = meta[M_OFF + i] + ((b - s0) << 6); gend = meta[M_OFF + i + 1]; }
    }
    if (e < 0) return;
    const int w = threadIdx.x >> 6, lane = threadIdx.x & 63;
    const int q = lane >> 4, r = lane & 15;

    int4v zero = {0, 0, 0, 0};
    int4v accg[4][4], accu[4][4];
    #pragma unroll
    for (int mi = 0; mi < 4; ++mi)
        #pragma unroll
        for (int i = 0; i < 4; ++i) { accg[mi][i] = zero; accu[mi][i] = zero; }

    const signed char* pbe = pb1 + (size_t)e * (64 * 512 * 16);
    for (int k0 = 0; k0 < HD; k0 += 64) {
        int4v a[4];
        #pragma unroll
        for (int mi = 0; mi < 4; ++mi)
            a[mi] = *(const int4v*)(xq + (size_t)(m0 + mi * 16 + r) * HD + k0 + q * 16);
        int kc = (k0 >> 4) + q;
        #pragma unroll
        for (int i = 0; i < 4; ++i) {
            int n = w * 64 + i * 16 + r;
            int4v bg = *(const int4v*)(pbe + (((size_t)kc * 512 + n) << 4));
            int4v bu = *(const int4v*)(pbe + (((size_t)kc * 512 + n + 256) << 4));
            #pragma unroll
            for (int mi = 0; mi < 4; ++mi) {
                accg[mi][i] = __builtin_amdgcn_mfma_i32_16x16x64_i8(a[mi], bg, accg[mi][i], 0, 0, 0);
                accu[mi][i] = __builtin_amdgcn_mfma_i32_16x16x64_i8(a[mi], bu, accu[mi][i], 0, 0, 0);
            }
        }
    }

    float gs[4], us[4];
    #pragma unroll
    for (int i = 0; i < 4; ++i) {
        int n = w * 64 + i * 16 + r;
        gs[i] = gsc[e * IE + n];
        us[i] = usc[e * IE + n];
    }
    float xsr[4][4];
    #pragma unroll
    for (int mi = 0; mi < 4; ++mi)
        #pragma unroll
        for (int g = 0; g < 4; ++g)
            xsr[mi][g] = xs[m0 + mi * 16 + q * 4 + g];

    float inter[4][4][4];
    float pm[4][4];
    #pragma unroll
    for (int mi = 0; mi < 4; ++mi)
        #pragma unroll
        for (int g = 0; g < 4; ++g) {
            float mx = 0.0f;
            #pragma unroll
            for (int i = 0; i < 4; ++i) {
                float gv = (float)accg[mi][i][g] * xsr[mi][g] * gs[i];   // (mm * x_s) * w_s
                float uv = (float)accu[mi][i][g] * xsr[mi][g] * us[i];
                float sg = gv / (1.0f + expf(-gv));                     // silu
                float vv = sg * uv;
                inter[mi][i][g] = vv;
                mx = fmaxf(mx, fabsf(vv));
            }
            #pragma unroll
            for (int s = 1; s < 16; s <<= 1) mx = fmaxf(mx, __shfl_xor(mx, s, 64));
            pm[mi][g] = mx;
        }

    __shared__ float pmax[4][64];
    __shared__ float rsc[64];
    if (r == 0) {
        #pragma unroll
        for (int mi = 0; mi < 4; ++mi)
            #pragma unroll
            for (int g = 0; g < 4; ++g)
                pmax[w][mi * 16 + q * 4 + g] = pm[mi][g];
    }
    __syncthreads();
    if (threadIdx.x < 64) {
        int row = threadIdx.x;
        float mx = fmaxf(fmaxf(pmax[0][row], pmax[1][row]), fmaxf(pmax[2][row], pmax[3][row]));
        float sc = fmaxf(mx / 127.0f, 1e-8f);
        rsc[row] = sc;
        if (m0 + row < gend) isc[m0 + row] = sc;
    }
    __syncthreads();
    #pragma unroll
    for (int mi = 0; mi < 4; ++mi)
        #pragma unroll
        for (int g = 0; g < 4; ++g) {
            int row = mi * 16 + q * 4 + g;
            int slot = m0 + row;
            if (slot < gend) {
                float sc = rsc[row];
                #pragma unroll
                for (int i = 0; i < 4; ++i) {
                    float t = rintf(inter[mi][i][g] / sc);
                    t = fminf(fmaxf(t, -128.0f), 127.0f);
                    iq[(size_t)slot * IE + w * 64 + i * 16 + r] = (signed char)(int)t;
                }
            }
        }
}

// GEMM2: Mtile=32, N=1024, K=256; scatter rows to out[perm[slot]]
__global__ __launch_bounds__(256) void k_gemm2(const signed char* __restrict__ iq,
                                               const signed char* __restrict__ pb2,
                                               const float* __restrict__ isc,
                                               const float* __restrict__ dsc,
                                               const int* __restrict__ meta,
                                               const int* __restrict__ perm,
                                               float* __restrict__ out) {
    int b = blockIdx.x;
    int e = -1, m0 = 0, gend = 0;
    #pragma unroll
    for (int i = 0; i < EN; ++i) {
        int s0 = meta[M_TS2 + i], s1 = meta[M_TS2 + i + 1];
        if (b >= s0 && b < s1) { e = i; m0 = meta[M_OFF + i] + ((b - s0) << 5); gend = meta[M_OFF + i + 1]; }
    }
    if (e < 0) return;
    const int w = threadIdx.x >> 6, lane = threadIdx.x & 63;
    const int q = lane >> 4, r = lane & 15;

    int4v zero = {0, 0, 0, 0};
    int4v acc[2][16];
    #pragma unroll
    for (int mi = 0; mi < 2; ++mi)
        #pragma unroll
        for (int i = 0; i < 16; ++i) acc[mi][i] = zero;

    const signed char* pbe = pb2 + (size_t)e * (16 * 1024 * 16);
    for (int k0 = 0; k0 < IE; k0 += 64) {
        int4v a[2];
        #pragma unroll
        for (int mi = 0; mi < 2; ++mi)
            a[mi] = *(const int4v*)(iq + (size_t)(m0 + mi * 16 + r) * IE + k0 + q * 16);
        int kc = (k0 >> 4) + q;
        #pragma unroll
        for (int i = 0; i < 16; ++i) {
            int n = w * 256 + i * 16 + r;
            int4v bb = *(const int4v*)(pbe + (((size_t)kc * 1024 + n) << 4));
            acc[0][i] = __builtin_amdgcn_mfma_i32_16x16x64_i8(a[0], bb, acc[0][i], 0, 0, 0);
            acc[1][i] = __builtin_amdgcn_mfma_i32_16x16x64_i8(a[1], bb, acc[1][i], 0, 0, 0);
        }
    }

    float ds[16];
    #pragma unroll
    for (int i = 0; i < 16; ++i)
        ds[i] = dsc[e * HD + w * 256 + i * 16 + r];
    float isr[2][4]; int tok[2][4];
    #pragma unroll
    for (int mi = 0; mi < 2; ++mi)
        #pragma unroll
        for (int g = 0; g < 4; ++g) {
            int slot = m0 + mi * 16 + q * 4 + g;
            isr[mi][g] = isc[slot];
            tok[mi][g] = perm[slot];
        }
    #pragma unroll
    for (int mi = 0; mi < 2; ++mi)
        #pragma unroll
        for (int g = 0; g < 4; ++g) {
            int slot = m0 + mi * 16 + q * 4 + g;
            if (slot < gend) {
                float vs = isr[mi][g];
                size_t ob = (size_t)tok[mi][g] * HD + w * 256 + r;
                #pragma unroll
                for (int i = 0; i < 16; ++i)
                    out[ob + i * 16] = (float)acc[mi][i][g] * vs * ds[i];
            }
        }
}

extern "C" void kernel_launch(void* const* d_in, const int* in_sizes, int n_in,
                              void* d_out, int out_size, void* d_ws, size_t ws_size,
                              hipStream_t stream) {
    const float* hidden = (const float*)d_in[0];
    const int*   ids    = (const int*)d_in[1];
    const int*   gq     = (const int*)d_in[2];
    const float* gsc    = (const float*)d_in[3];
    const int*   uq     = (const int*)d_in[4];
    const float* usc    = (const float*)d_in[5];
    const int*   dq     = (const int*)d_in[6];
    const float* dsc    = (const float*)d_in[7];
    const int*   t2e    = (const int*)d_in[8];
    float* out = (float*)d_out;

    char* ws = (char*)d_ws;
    signed char* xq  = (signed char*)(ws + XQ_OFF);
    signed char* iq  = (signed char*)(ws + IQ_OFF);
    signed char* pb1 = (signed char*)(ws + PB1_OFF);
    signed char* pb2 = (signed char*)(ws + PB2_OFF);
    int*   perm = (int*)(ws + PERM_OFF);
    float* xs   = (float*)(ws + XS_OFF);
    float* isc  = (float*)(ws + IS_OFF);
    int*   meta = (int*)(ws + META_OFF);

    k_init<<<1, 64, 0, stream>>>(meta);
    k_hist<<<64, 256, 0, stream>>>(ids, t2e, meta);
    k_offsets<<<1, 1, 0, stream>>>(meta);
    k_assign<<<64, 256, 0, stream>>>(ids, t2e, meta, perm);
    k_repack<<<24576, 256, 0, stream>>>(gq, uq, dq, pb1, pb2);
    k_quant<<<4096, 256, 0, stream>>>(hidden, perm, xq, xs);
    k_gemm1<<<264, 256, 0, stream>>>(xq, pb1, xs, gsc, usc, meta, iq, isc);
    k_gemm2<<<520, 256, 0, stream>>>(iq, pb2, isc, dsc, meta, perm, out);
}

// Round 2
// 249.366 us; speedup vs baseline: 1.3915x; 1.3915x over previous
//
#include <hip/hip_runtime.h>
#include <hip/hip_bf16.h>

typedef int   int4v   __attribute__((ext_vector_type(4)));
typedef float float4v __attribute__((ext_vector_type(4)));

#define T_TOK 16384
#define TPAD  16448     // T + 64 pad so ragged GEMM tiles can over-read safely
#define HD    1024
#define IE    256
#define EN    8
#define VSZ   100000

// meta[] int indices
#define M_OFF 16   // [9] group offsets
#define M_TS1 25   // [9] gemm1 tile-start prefix (Mtile=64)
#define M_TS2 34   // [9] gemm2 tile-start prefix (Mtile=32)

// ws byte offsets (all 16-aligned)
#define XQ_OFF   0ull           // TPAD*1024 int8
#define IQ_OFF   16842752ull    // TPAD*256 int8
#define PB1_OFF  21053440ull    // 8*64*512*16 int8 (gate|up packed)
#define PB2_OFF  25247744ull    // 8*16*1024*16 int8 (down packed)
#define PERM_OFF 27344896ull    // TPAD int32
#define XS_OFF   27410688ull    // TPAD float
#define IS_OFF   27476480ull    // TPAD float
#define META_OFF 27542272ull    // 64 int32
#define BC_OFF   27542528ull    // 64*8 int32 per-block histograms
#define BB_OFF   27544576ull    // 64*8 int32 per-block bases

// per-block histogram -> bc[block][e]  (no global atomics)
__global__ void k_hist(const int* __restrict__ ids, const int* __restrict__ t2e,
                       int* __restrict__ bc) {
    __shared__ int h[EN];
    if (threadIdx.x < EN) h[threadIdx.x] = 0;
    __syncthreads();
    int t = blockIdx.x * 256 + threadIdx.x;
    int id = ids[t]; id = min(max(id, 0), VSZ - 1);
    atomicAdd(&h[t2e[id]], 1);
    __syncthreads();
    if (threadIdx.x < EN) bc[blockIdx.x * EN + threadIdx.x] = h[threadIdx.x];
}

// single block, 8 waves (one per expert): prefix over 64 blocks via shuffles,
// then group offsets + tile prefixes, then per-block bases.
__global__ __launch_bounds__(512) void k_scan(const int* __restrict__ bc,
                                              int* __restrict__ bbase,
                                              int* __restrict__ meta) {
    int e = threadIdx.x >> 6;    // wave = expert
    int b = threadIdx.x & 63;    // lane = source block
    int c = bc[b * EN + e];
    int inc = c;
    #pragma unroll
    for (int s = 1; s < 64; s <<= 1) {
        int v = __shfl_up(inc, s, 64);
        if (b >= s) inc += v;
    }
    int exc = inc - c;
    __shared__ int tot[EN];
    __shared__ int goff[EN];
    if (b == 63) tot[e] = inc;
    __syncthreads();
    if (threadIdx.x == 0) {
        int off = 0, t1 = 0, t2 = 0;
        meta[M_OFF] = 0; meta[M_TS1] = 0; meta[M_TS2] = 0;
        #pragma unroll
        for (int i = 0; i < EN; ++i) {
            goff[i] = off;
            int cc = tot[i];
            off += cc; t1 += (cc + 63) >> 6; t2 += (cc + 31) >> 5;
            meta[M_OFF + i + 1] = off;
            meta[M_TS1 + i + 1] = t1;
            meta[M_TS2 + i + 1] = t2;
        }
    }
    __syncthreads();
    bbase[b * EN + e] = goff[e] + exc;
}

// LDS cursors seeded from bbase -> zero global atomics
__global__ void k_assign(const int* __restrict__ ids, const int* __restrict__ t2e,
                         const int* __restrict__ bbase, int* __restrict__ perm) {
    __shared__ int cur[EN];
    if (threadIdx.x < EN) cur[threadIdx.x] = bbase[blockIdx.x * EN + threadIdx.x];
    __syncthreads();
    int t = blockIdx.x * 256 + threadIdx.x;
    int id = ids[t]; id = min(max(id, 0), VSZ - 1);
    int e = t2e[id];
    int slot = atomicAdd(&cur[e], 1);
    perm[slot] = t;
}

// one thread builds one full 16B fragment: 16 coalesced dword loads + 1 dwordx4 store
// fragment layout: elem(k,n) at ((k>>4)*N + n)*16 + (k&15)
__global__ __launch_bounds__(256) void k_repack(const int* __restrict__ gq,
                                                const int* __restrict__ uq,
                                                const int* __restrict__ dq,
                                                signed char* __restrict__ pb1,
                                                signed char* __restrict__ pb2) {
    int idx = blockIdx.x * 256 + threadIdx.x;   // 0 .. 393215
    if (idx < 262144) {                          // gate|up fragments [8][64][512]
        int n = idx & 511, kc = (idx >> 9) & 63, e = idx >> 15;
        const int* src = (n < 256) ? gq + (((size_t)((e << 10) + (kc << 4)) << 8) + n)
                                   : uq + (((size_t)((e << 10) + (kc << 4)) << 8) + (n - 256));
        int4v pk;
        #pragma unroll
        for (int jj = 0; jj < 4; ++jj) {
            int b0 = src[(size_t)(jj * 4 + 0) << 8], b1 = src[(size_t)(jj * 4 + 1) << 8];
            int b2 = src[(size_t)(jj * 4 + 2) << 8], b3 = src[(size_t)(jj * 4 + 3) << 8];
            pk[jj] = (b0 & 255) | ((b1 & 255) << 8) | ((b2 & 255) << 16) | (b3 << 24);
        }
        *(int4v*)(pb1 + ((size_t)((((e << 6) + kc) << 9) + n) << 4)) = pk;
    } else {                                     // down fragments [8][16][1024]
        int j = idx - 262144;
        int n = j & 1023, kc = (j >> 10) & 15, e = j >> 14;
        const int* src = dq + (((size_t)((e << 8) + (kc << 4)) << 10) + n);
        int4v pk;
        #pragma unroll
        for (int jj = 0; jj < 4; ++jj) {
            int b0 = src[(size_t)(jj * 4 + 0) << 10], b1 = src[(size_t)(jj * 4 + 1) << 10];
            int b2 = src[(size_t)(jj * 4 + 2) << 10], b3 = src[(size_t)(jj * 4 + 3) << 10];
            pk[jj] = (b0 & 255) | ((b1 & 255) << 8) | ((b2 & 255) << 16) | (b3 << 24);
        }
        *(int4v*)(pb2 + ((size_t)((((e << 4) + kc) << 10) + n) << 4)) = pk;
    }
}

// one wave per slot: gather token row, rowwise int8 quantize (bit-exact vs ref)
__global__ __launch_bounds__(256) void k_quant(const float* __restrict__ hidden,
                                               const int* __restrict__ perm,
                                               signed char* __restrict__ xq,
                                               float* __restrict__ xs) {
    int w = threadIdx.x >> 6, lane = threadIdx.x & 63;
    int slot = blockIdx.x * 4 + w;
    int token = perm[slot];
    const float* row = hidden + (size_t)token * HD;
    float v[16];
    #pragma unroll
    for (int j = 0; j < 4; ++j) {
        float4v f = *(const float4v*)(row + lane * 16 + j * 4);
        v[j*4+0] = f[0]; v[j*4+1] = f[1]; v[j*4+2] = f[2]; v[j*4+3] = f[3];
    }
    float mx = 0.0f;
    #pragma unroll
    for (int j = 0; j < 16; ++j) mx = fmaxf(mx, fabsf(v[j]));
    #pragma unroll
    for (int s = 1; s < 64; s <<= 1) mx = fmaxf(mx, __shfl_xor(mx, s, 64));
    float sc = fmaxf(mx / 127.0f, 1e-8f);
    if (lane == 0) xs[slot] = sc;
    int4v pk;
    #pragma unroll
    for (int j = 0; j < 4; ++j) {
        int b[4];
        #pragma unroll
        for (int u = 0; u < 4; ++u) {
            float t = rintf(v[j*4+u] / sc);           // round-half-even == jnp.round
            t = fminf(fmaxf(t, -128.0f), 127.0f);
            b[u] = (int)t;
        }
        pk[j] = (b[0] & 255) | ((b[1] & 255) << 8) | ((b[2] & 255) << 16) | (b[3] << 24);
    }
    *(int4v*)(xq + (size_t)slot * HD + lane * 16) = pk;
}

// GEMM1: per block Mtile=64, N=512 (gate 0..255 | up 256..511), K=1024.
__global__ __launch_bounds__(256) void k_gemm1(const signed char* __restrict__ xq,
                                               const signed char* __restrict__ pb1,
                                               const float* __restrict__ xs,
                                               const float* __restrict__ gsc,
                                               const float* __restrict__ usc,
                                               const int* __restrict__ meta,
                                               signed char* __restrict__ iq,
                                               float* __restrict__ isc) {
    int b = blockIdx.x;
    int e = -1, m0 = 0, gend = 0;
    #pragma unroll
    for (int i = 0; i < EN; ++i) {
        int s0 = meta[M_TS1 + i], s1 = meta[M_TS1 + i + 1];
        if (b >= s0 && b < s1) { e = i; m0 = meta[M_OFF + i] + ((b - s0) << 6); gend = meta[M_OFF + i + 1]; }
    }
    if (e < 0) return;
    const int w = threadIdx.x >> 6, lane = threadIdx.x & 63;
    const int q = lane >> 4, r = lane & 15;

    int4v zero = {0, 0, 0, 0};
    int4v accg[4][4], accu[4][4];
    #pragma unroll
    for (int mi = 0; mi < 4; ++mi)
        #pragma unroll
        for (int i = 0; i < 4; ++i) { accg[mi][i] = zero; accu[mi][i] = zero; }

    const signed char* pbe = pb1 + (size_t)e * (64 * 512 * 16);
    for (int k0 = 0; k0 < HD; k0 += 64) {
        int4v a[4];
        #pragma unroll
        for (int mi = 0; mi < 4; ++mi)
            a[mi] = *(const int4v*)(xq + (size_t)(m0 + mi * 16 + r) * HD + k0 + q * 16);
        int kc = (k0 >> 4) + q;
        #pragma unroll
        for (int i = 0; i < 4; ++i) {
            int n = w * 64 + i * 16 + r;
            int4v bg = *(const int4v*)(pbe + (((size_t)kc * 512 + n) << 4));
            int4v bu = *(const int4v*)(pbe + (((size_t)kc * 512 + n + 256) << 4));
            #pragma unroll
            for (int mi = 0; mi < 4; ++mi) {
                accg[mi][i] = __builtin_amdgcn_mfma_i32_16x16x64_i8(a[mi], bg, accg[mi][i], 0, 0, 0);
                accu[mi][i] = __builtin_amdgcn_mfma_i32_16x16x64_i8(a[mi], bu, accu[mi][i], 0, 0, 0);
            }
        }
    }

    float gs[4], us[4];
    #pragma unroll
    for (int i = 0; i < 4; ++i) {
        int n = w * 64 + i * 16 + r;
        gs[i] = gsc[e * IE + n];
        us[i] = usc[e * IE + n];
    }
    float xsr[4][4];
    #pragma unroll
    for (int mi = 0; mi < 4; ++mi)
        #pragma unroll
        for (int g = 0; g < 4; ++g)
            xsr[mi][g] = xs[m0 + mi * 16 + q * 4 + g];

    float inter[4][4][4];
    float pm[4][4];
    #pragma unroll
    for (int mi = 0; mi < 4; ++mi)
        #pragma unroll
        for (int g = 0; g < 4; ++g) {
            float mx = 0.0f;
            #pragma unroll
            for (int i = 0; i < 4; ++i) {
                float gv = (float)accg[mi][i][g] * xsr[mi][g] * gs[i];   // (mm * x_s) * w_s
                float uv = (float)accu[mi][i][g] * xsr[mi][g] * us[i];
                float sg = gv / (1.0f + expf(-gv));                     // silu
                float vv = sg * uv;
                inter[mi][i][g] = vv;
                mx = fmaxf(mx, fabsf(vv));
            }
            #pragma unroll
            for (int s = 1; s < 16; s <<= 1) mx = fmaxf(mx, __shfl_xor(mx, s, 64));
            pm[mi][g] = mx;
        }

    __shared__ float pmax[4][64];
    __shared__ float rsc[64];
    if (r == 0) {
        #pragma unroll
        for (int mi = 0; mi < 4; ++mi)
            #pragma unroll
            for (int g = 0; g < 4; ++g)
                pmax[w][mi * 16 + q * 4 + g] = pm[mi][g];
    }
    __syncthreads();
    if (threadIdx.x < 64) {
        int row = threadIdx.x;
        float mx = fmaxf(fmaxf(pmax[0][row], pmax[1][row]), fmaxf(pmax[2][row], pmax[3][row]));
        float sc = fmaxf(mx / 127.0f, 1e-8f);
        rsc[row] = sc;
        if (m0 + row < gend) isc[m0 + row] = sc;
    }
    __syncthreads();
    #pragma unroll
    for (int mi = 0; mi < 4; ++mi)
        #pragma unroll
        for (int g = 0; g < 4; ++g) {
            int row = mi * 16 + q * 4 + g;
            int slot = m0 + row;
            if (slot < gend) {
                float sc = rsc[row];
                #pragma unroll
                for (int i = 0; i < 4; ++i) {
                    float t = rintf(inter[mi][i][g] / sc);
                    t = fminf(fmaxf(t, -128.0f), 127.0f);
                    iq[(size_t)slot * IE + w * 64 + i * 16 + r] = (signed char)(int)t;
                }
            }
        }
}

// GEMM2: Mtile=32, N=1024, K=256; scatter rows to out[perm[slot]]
__global__ __launch_bounds__(256) void k_gemm2(const signed char* __restrict__ iq,
                                               const signed char* __restrict__ pb2,
                                               const float* __restrict__ isc,
                                               const float* __restrict__ dsc,
                                               const int* __restrict__ meta,
                                               const int* __restrict__ perm,
                                               float* __restrict__ out) {
    int b = blockIdx.x;
    int e = -1, m0 = 0, gend = 0;
    #pragma unroll
    for (int i = 0; i < EN; ++i) {
        int s0 = meta[M_TS2 + i], s1 = meta[M_TS2 + i + 1];
        if (b >= s0 && b < s1) { e = i; m0 = meta[M_OFF + i] + ((b - s0) << 5); gend = meta[M_OFF + i + 1]; }
    }
    if (e < 0) return;
    const int w = threadIdx.x >> 6, lane = threadIdx.x & 63;
    const int q = lane >> 4, r = lane & 15;

    int4v zero = {0, 0, 0, 0};
    int4v acc[2][16];
    #pragma unroll
    for (int mi = 0; mi < 2; ++mi)
        #pragma unroll
        for (int i = 0; i < 16; ++i) acc[mi][i] = zero;

    const signed char* pbe = pb2 + (size_t)e * (16 * 1024 * 16);
    for (int k0 = 0; k0 < IE; k0 += 64) {
        int4v a[2];
        #pragma unroll
        for (int mi = 0; mi < 2; ++mi)
            a[mi] = *(const int4v*)(iq + (size_t)(m0 + mi * 16 + r) * IE + k0 + q * 16);
        int kc = (k0 >> 4) + q;
        #pragma unroll
        for (int i = 0; i < 16; ++i) {
            int n = w * 256 + i * 16 + r;
            int4v bb = *(const int4v*)(pbe + (((size_t)kc * 1024 + n) << 4));
            acc[0][i] = __builtin_amdgcn_mfma_i32_16x16x64_i8(a[0], bb, acc[0][i], 0, 0, 0);
            acc[1][i] = __builtin_amdgcn_mfma_i32_16x16x64_i8(a[1], bb, acc[1][i], 0, 0, 0);
        }
    }

    float ds[16];
    #pragma unroll
    for (int i = 0; i < 16; ++i)
        ds[i] = dsc[e * HD + w * 256 + i * 16 + r];
    float isr[2][4]; int tok[2][4];
    #pragma unroll
    for (int mi = 0; mi < 2; ++mi)
        #pragma unroll
        for (int g = 0; g < 4; ++g) {
            int slot = m0 + mi * 16 + q * 4 + g;
            isr[mi][g] = isc[slot];
            tok[mi][g] = perm[slot];
        }
    #pragma unroll
    for (int mi = 0; mi < 2; ++mi)
        #pragma unroll
        for (int g = 0; g < 4; ++g) {
            int slot = m0 + mi * 16 + q * 4 + g;
            if (slot < gend) {
                float vs = isr[mi][g];
                size_t ob = (size_t)tok[mi][g] * HD + w * 256 + r;
                #pragma unroll
                for (int i = 0; i < 16; ++i)
                    out[ob + i * 16] = (float)acc[mi][i][g] * vs * ds[i];
            }
        }
}

extern "C" void kernel_launch(void* const* d_in, const int* in_sizes, int n_in,
                              void* d_out, int out_size, void* d_ws, size_t ws_size,
                              hipStream_t stream) {
    const float* hidden = (const float*)d_in[0];
    const int*   ids    = (const int*)d_in[1];
    const int*   gq     = (const int*)d_in[2];
    const float* gsc    = (const float*)d_in[3];
    const int*   uq     = (const int*)d_in[4];
    const float* usc    = (const float*)d_in[5];
    const int*   dq     = (const int*)d_in[6];
    const float* dsc    = (const float*)d_in[7];
    const int*   t2e    = (const int*)d_in[8];
    float* out = (float*)d_out;

    char* ws = (char*)d_ws;
    signed char* xq  = (signed char*)(ws + XQ_OFF);
    signed char* iq  = (signed char*)(ws + IQ_OFF);
    signed char* pb1 = (signed char*)(ws + PB1_OFF);
    signed char* pb2 = (signed char*)(ws + PB2_OFF);
    int*   perm = (int*)(ws + PERM_OFF);
    float* xs   = (float*)(ws + XS_OFF);
    float* isc  = (float*)(ws + IS_OFF);
    int*   meta = (int*)(ws + META_OFF);
    int*   bc   = (int*)(ws + BC_OFF);
    int*   bbase= (int*)(ws + BB_OFF);

    k_hist<<<64, 256, 0, stream>>>(ids, t2e, bc);
    k_scan<<<1, 512, 0, stream>>>(bc, bbase, meta);
    k_assign<<<64, 256, 0, stream>>>(ids, t2e, bbase, perm);
    k_repack<<<1536, 256, 0, stream>>>(gq, uq, dq, pb1, pb2);
    k_quant<<<4096, 256, 0, stream>>>(hidden, perm, xq, xs);
    k_gemm1<<<264, 256, 0, stream>>>(xq, pb1, xs, gsc, usc, meta, iq, isc);
    k_gemm2<<<520, 256, 0, stream>>>(iq, pb2, isc, dsc, meta, perm, out);
}

// Round 3
// 211.384 us; speedup vs baseline: 1.6416x; 1.1797x over previous
//
#include <hip/hip_runtime.h>
#include <hip/hip_bf16.h>

typedef int   int4v   __attribute__((ext_vector_type(4)));
typedef float float4v __attribute__((ext_vector_type(4)));

#define T_TOK 16384
#define TPAD  16448     // T + 64 pad so ragged GEMM tiles can over-read safely
#define HD    1024
#define IE    256
#define EN    8
#define VSZ   100000

// meta[] int indices
#define M_OFF 16   // [9] group offsets
#define M_TS1 25   // [9] gemm1 tile-start prefix (Mtile=64)
#define M_TS2 34   // [9] gemm2 tile-start prefix (Mtile=32)

// ws byte offsets (all 16-aligned)
#define XQ_OFF   0ull           // TPAD*1024 int8
#define IQ_OFF   16842752ull    // TPAD*256 int8
#define PB1_OFF  21053440ull    // 8*64*512*16 int8 (gate|up packed)
#define PB2_OFF  25247744ull    // 8*16*1024*16 int8 (down packed)
#define PERM_OFF 27344896ull    // TPAD int32
#define XS_OFF   27410688ull    // TPAD float
#define IS_OFF   27476480ull    // TPAD float
#define META_OFF 27542272ull    // 64 int32
#define BC_OFF   27542528ull    // 64*8 int32 per-block histograms
#define BB_OFF   27544576ull    // 64*8 int32 per-block bases

// async global->LDS, 16B per lane; LDS dest = wave-uniform base + lane*16
__device__ __forceinline__ void gload16(const void* g, void* l) {
    __builtin_amdgcn_global_load_lds(
        (const __attribute__((address_space(1))) unsigned int*)g,
        (__attribute__((address_space(3))) unsigned int*)l,
        16, 0, 0);
}

// per-block histogram -> bc[block][e]  (no global atomics)
__global__ void k_hist(const int* __restrict__ ids, const int* __restrict__ t2e,
                       int* __restrict__ bc) {
    __shared__ int h[EN];
    if (threadIdx.x < EN) h[threadIdx.x] = 0;
    __syncthreads();
    int t = blockIdx.x * 256 + threadIdx.x;
    int id = ids[t]; id = min(max(id, 0), VSZ - 1);
    atomicAdd(&h[t2e[id]], 1);
    __syncthreads();
    if (threadIdx.x < EN) bc[blockIdx.x * EN + threadIdx.x] = h[threadIdx.x];
}

// single block, 8 waves (one per expert): prefix over 64 blocks via shuffles
__global__ __launch_bounds__(512) void k_scan(const int* __restrict__ bc,
                                              int* __restrict__ bbase,
                                              int* __restrict__ meta) {
    int e = threadIdx.x >> 6;
    int b = threadIdx.x & 63;
    int c = bc[b * EN + e];
    int inc = c;
    #pragma unroll
    for (int s = 1; s < 64; s <<= 1) {
        int v = __shfl_up(inc, s, 64);
        if (b >= s) inc += v;
    }
    int exc = inc - c;
    __shared__ int tot[EN];
    __shared__ int goff[EN];
    if (b == 63) tot[e] = inc;
    __syncthreads();
    if (threadIdx.x == 0) {
        int off = 0, t1 = 0, t2 = 0;
        meta[M_OFF] = 0; meta[M_TS1] = 0; meta[M_TS2] = 0;
        #pragma unroll
        for (int i = 0; i < EN; ++i) {
            goff[i] = off;
            int cc = tot[i];
            off += cc; t1 += (cc + 63) >> 6; t2 += (cc + 31) >> 5;
            meta[M_OFF + i + 1] = off;
            meta[M_TS1 + i + 1] = t1;
            meta[M_TS2 + i + 1] = t2;
        }
    }
    __syncthreads();
    bbase[b * EN + e] = goff[e] + exc;
}

// LDS cursors seeded from bbase -> zero global atomics
__global__ void k_assign(const int* __restrict__ ids, const int* __restrict__ t2e,
                         const int* __restrict__ bbase, int* __restrict__ perm) {
    __shared__ int cur[EN];
    if (threadIdx.x < EN) cur[threadIdx.x] = bbase[blockIdx.x * EN + threadIdx.x];
    __syncthreads();
    int t = blockIdx.x * 256 + threadIdx.x;
    int id = ids[t]; id = min(max(id, 0), VSZ - 1);
    int e = t2e[id];
    int slot = atomicAdd(&cur[e], 1);
    perm[slot] = t;
}

// one thread builds one full 16B fragment
// fragment layout: elem(k,n) at ((k>>4)*N + n)*16 + (k&15)
__global__ __launch_bounds__(256) void k_repack(const int* __restrict__ gq,
                                                const int* __restrict__ uq,
                                                const int* __restrict__ dq,
                                                signed char* __restrict__ pb1,
                                                signed char* __restrict__ pb2) {
    int idx = blockIdx.x * 256 + threadIdx.x;   // 0 .. 393215
    if (idx < 262144) {                          // gate|up fragments [8][64][512]
        int n = idx & 511, kc = (idx >> 9) & 63, e = idx >> 15;
        const int* src = (n < 256) ? gq + (((size_t)((e << 10) + (kc << 4)) << 8) + n)
                                   : uq + (((size_t)((e << 10) + (kc << 4)) << 8) + (n - 256));
        int4v pk;
        #pragma unroll
        for (int jj = 0; jj < 4; ++jj) {
            int b0 = src[(size_t)(jj * 4 + 0) << 8], b1 = src[(size_t)(jj * 4 + 1) << 8];
            int b2 = src[(size_t)(jj * 4 + 2) << 8], b3 = src[(size_t)(jj * 4 + 3) << 8];
            pk[jj] = (b0 & 255) | ((b1 & 255) << 8) | ((b2 & 255) << 16) | (b3 << 24);
        }
        *(int4v*)(pb1 + ((size_t)((((e << 6) + kc) << 9) + n) << 4)) = pk;
    } else {                                     // down fragments [8][16][1024]
        int j = idx - 262144;
        int n = j & 1023, kc = (j >> 10) & 15, e = j >> 14;
        const int* src = dq + (((size_t)((e << 8) + (kc << 4)) << 10) + n);
        int4v pk;
        #pragma unroll
        for (int jj = 0; jj < 4; ++jj) {
            int b0 = src[(size_t)(jj * 4 + 0) << 10], b1 = src[(size_t)(jj * 4 + 1) << 10];
            int b2 = src[(size_t)(jj * 4 + 2) << 10], b3 = src[(size_t)(jj * 4 + 3) << 10];
            pk[jj] = (b0 & 255) | ((b1 & 255) << 8) | ((b2 & 255) << 16) | (b3 << 24);
        }
        *(int4v*)(pb2 + ((size_t)((((e << 4) + kc) << 10) + n) << 4)) = pk;
    }
}

// one wave per slot: gather token row, rowwise int8 quantize (bit-exact vs ref)
__global__ __launch_bounds__(256) void k_quant(const float* __restrict__ hidden,
                                               const int* __restrict__ perm,
                                               signed char* __restrict__ xq,
                                               float* __restrict__ xs) {
    int w = threadIdx.x >> 6, lane = threadIdx.x & 63;
    int slot = blockIdx.x * 4 + w;
    int token = perm[slot];
    const float* row = hidden + (size_t)token * HD;
    float v[16];
    #pragma unroll
    for (int j = 0; j < 4; ++j) {
        float4v f = *(const float4v*)(row + lane * 16 + j * 4);
        v[j*4+0] = f[0]; v[j*4+1] = f[1]; v[j*4+2] = f[2]; v[j*4+3] = f[3];
    }
    float mx = 0.0f;
    #pragma unroll
    for (int j = 0; j < 16; ++j) mx = fmaxf(mx, fabsf(v[j]));
    #pragma unroll
    for (int s = 1; s < 64; s <<= 1) mx = fmaxf(mx, __shfl_xor(mx, s, 64));
    float sc = fmaxf(mx / 127.0f, 1e-8f);
    if (lane == 0) xs[slot] = sc;
    int4v pk;
    #pragma unroll
    for (int j = 0; j < 4; ++j) {
        int b[4];
        #pragma unroll
        for (int u = 0; u < 4; ++u) {
            float t = rintf(v[j*4+u] / sc);           // round-half-even == jnp.round
            t = fminf(fmaxf(t, -128.0f), 127.0f);
            b[u] = (int)t;
        }
        pk[j] = (b[0] & 255) | ((b[1] & 255) << 8) | ((b[2] & 255) << 16) | (b[3] << 24);
    }
    *(int4v*)(xq + (size_t)slot * HD + lane * 16) = pk;
}

// GEMM1: Mtile=64, N=512 (gate|up), K=1024. LDS double-buffered async staging.
// B LDS slot s=kcl*512+n' holds frag(kcl, n = n'^((kcl&1)*8)) -> <=4-way conflicts.
// A LDS: row*64 + c'*16 holds A(row, q = c'^(row&3)).
__global__ __launch_bounds__(256, 2) void k_gemm1(const signed char* __restrict__ xq,
                                                  const signed char* __restrict__ pb1,
                                                  const float* __restrict__ xs,
                                                  const float* __restrict__ gsc,
                                                  const float* __restrict__ usc,
                                                  const int* __restrict__ meta,
                                                  signed char* __restrict__ iq,
                                                  float* __restrict__ isc) {
    int b = blockIdx.x;
    int e = -1, m0 = 0, gend = 0;
    #pragma unroll
    for (int i = 0; i < EN; ++i) {
        int s0 = meta[M_TS1 + i], s1 = meta[M_TS1 + i + 1];
        if (b >= s0 && b < s1) { e = i; m0 = meta[M_OFF + i] + ((b - s0) << 6); gend = meta[M_OFF + i + 1]; }
    }
    if (e < 0) return;
    const int w = threadIdx.x >> 6, lane = threadIdx.x & 63;
    const int q = lane >> 4, r = lane & 15;

    __shared__ signed char lB[2][32768];
    __shared__ signed char lA[2][4096];
    __shared__ float pmax[4][64];
    __shared__ float rsc[64];

    const signed char* pbe = pb1 + (size_t)e * (64 * 512 * 16);
    const int arow = (w << 4) + (lane >> 2);          // staging row 0..63
    const int acq  = (lane & 3) ^ ((lane >> 2) & 3);  // swizzled q-slot content
    const signed char* ga_base = xq + (size_t)(m0 + arow) * HD + (acq << 4);

    #define G1_STAGE(buf, kt)                                                          \
        {                                                                              \
            int kc0 = (kt) << 2;                                                       \
            _Pragma("unroll")                                                          \
            for (int j = 0; j < 8; ++j) {                                              \
                int n = ((j << 6) + lane) ^ ((w & 1) << 3);                            \
                gload16(pbe + (((size_t)(kc0 + w) * 512 + n) << 4),                    \
                        &lB[buf][((w << 3) + j) << 10]);                               \
            }                                                                          \
            gload16(ga_base + ((kt) << 6), &lA[buf][w << 10]);                         \
        }

    int4v zero = {0, 0, 0, 0};
    int4v accg[4][4], accu[4][4];
    #pragma unroll
    for (int mi = 0; mi < 4; ++mi)
        #pragma unroll
        for (int i = 0; i < 4; ++i) { accg[mi][i] = zero; accu[mi][i] = zero; }

    G1_STAGE(0, 0);
    for (int kt = 0; kt < 16; ++kt) {
        int cur = kt & 1;
        if (kt < 15) G1_STAGE(cur ^ 1, kt + 1);
        __syncthreads();
        int4v a[4];
        #pragma unroll
        for (int mi = 0; mi < 4; ++mi)
            a[mi] = *(const int4v*)&lA[cur][(((mi << 4) + r) << 6) + ((q ^ (r & 3)) << 4)];
        #pragma unroll
        for (int i = 0; i < 4; ++i) {
            int n = (w << 6) + (i << 4) + r;
            int sg = (q << 9) + (n ^ ((q & 1) << 3));
            int su = (q << 9) + ((n + 256) ^ ((q & 1) << 3));
            int4v bg = *(const int4v*)&lB[cur][sg << 4];
            int4v bu = *(const int4v*)&lB[cur][su << 4];
            #pragma unroll
            for (int mi = 0; mi < 4; ++mi) {
                accg[mi][i] = __builtin_amdgcn_mfma_i32_16x16x64_i8(a[mi], bg, accg[mi][i], 0, 0, 0);
                accu[mi][i] = __builtin_amdgcn_mfma_i32_16x16x64_i8(a[mi], bu, accu[mi][i], 0, 0, 0);
            }
        }
        __syncthreads();
    }
    #undef G1_STAGE

    float gs[4], us[4];
    #pragma unroll
    for (int i = 0; i < 4; ++i) {
        int n = (w << 6) + (i << 4) + r;
        gs[i] = gsc[e * IE + n];
        us[i] = usc[e * IE + n];
    }
    float xsr[4][4];
    #pragma unroll
    for (int mi = 0; mi < 4; ++mi)
        #pragma unroll
        for (int g = 0; g < 4; ++g)
            xsr[mi][g] = xs[m0 + mi * 16 + q * 4 + g];

    float inter[4][4][4];
    float pm[4][4];
    #pragma unroll
    for (int mi = 0; mi < 4; ++mi)
        #pragma unroll
        for (int g = 0; g < 4; ++g) {
            float mx = 0.0f;
            #pragma unroll
            for (int i = 0; i < 4; ++i) {
                float gv = (float)accg[mi][i][g] * xsr[mi][g] * gs[i];
                float uv = (float)accu[mi][i][g] * xsr[mi][g] * us[i];
                float sg = gv / (1.0f + expf(-gv));
                float vv = sg * uv;
                inter[mi][i][g] = vv;
                mx = fmaxf(mx, fabsf(vv));
            }
            #pragma unroll
            for (int s = 1; s < 16; s <<= 1) mx = fmaxf(mx, __shfl_xor(mx, s, 64));
            pm[mi][g] = mx;
        }

    if (r == 0) {
        #pragma unroll
        for (int mi = 0; mi < 4; ++mi)
            #pragma unroll
            for (int g = 0; g < 4; ++g)
                pmax[w][mi * 16 + q * 4 + g] = pm[mi][g];
    }
    __syncthreads();
    if (threadIdx.x < 64) {
        int row = threadIdx.x;
        float mx = fmaxf(fmaxf(pmax[0][row], pmax[1][row]), fmaxf(pmax[2][row], pmax[3][row]));
        float sc = fmaxf(mx / 127.0f, 1e-8f);
        rsc[row] = sc;
        if (m0 + row < gend) isc[m0 + row] = sc;
    }
    __syncthreads();
    #pragma unroll
    for (int mi = 0; mi < 4; ++mi)
        #pragma unroll
        for (int g = 0; g < 4; ++g) {
            int row = mi * 16 + q * 4 + g;
            int slot = m0 + row;
            if (slot < gend) {
                float sc = rsc[row];
                #pragma unroll
                for (int i = 0; i < 4; ++i) {
                    float t = rintf(inter[mi][i][g] / sc);
                    t = fminf(fmaxf(t, -128.0f), 127.0f);
                    iq[(size_t)slot * IE + (w << 6) + (i << 4) + r] = (signed char)(int)t;
                }
            }
        }
}

// GEMM2: Mtile=32, Ntile=512 (2 n-halves), K=256. Same staging scheme.
__global__ __launch_bounds__(256, 2) void k_gemm2(const signed char* __restrict__ iq,
                                                  const signed char* __restrict__ pb2,
                                                  const float* __restrict__ isc,
                                                  const float* __restrict__ dsc,
                                                  const int* __restrict__ meta,
                                                  const int* __restrict__ perm,
                                                  float* __restrict__ out) {
    int tile = blockIdx.x >> 1, nh = blockIdx.x & 1;
    int e = -1, m0 = 0, gend = 0;
    #pragma unroll
    for (int i = 0; i < EN; ++i) {
        int s0 = meta[M_TS2 + i], s1 = meta[M_TS2 + i + 1];
        if (tile >= s0 && tile < s1) { e = i; m0 = meta[M_OFF + i] + ((tile - s0) << 5); gend = meta[M_OFF + i + 1]; }
    }
    if (e < 0) return;
    const int w = threadIdx.x >> 6, lane = threadIdx.x & 63;
    const int q = lane >> 4, r = lane & 15;

    __shared__ signed char lB[2][32768];
    __shared__ signed char lA[2][2048];

    const signed char* pbe = pb2 + (size_t)e * (16 * 1024 * 16);
    const int arow = (w << 4) + (lane >> 2);
    const int acq  = (lane & 3) ^ ((lane >> 2) & 3);
    const signed char* ga_base = iq + (size_t)(m0 + arow) * IE + (acq << 4);

    #define G2_STAGE(buf, kt)                                                          \
        {                                                                              \
            int kc0 = (kt) << 2;                                                       \
            _Pragma("unroll")                                                          \
            for (int j = 0; j < 8; ++j) {                                              \
                int n = ((j << 6) + lane) ^ ((w & 1) << 3);                            \
                gload16(pbe + (((size_t)(kc0 + w) * 1024 + (nh << 9) + n) << 4),       \
                        &lB[buf][((w << 3) + j) << 10]);                               \
            }                                                                          \
            if (w < 2) gload16(ga_base + ((kt) << 6), &lA[buf][w << 10]);              \
        }

    int4v zero = {0, 0, 0, 0};
    int4v acc[2][8];
    #pragma unroll
    for (int mi = 0; mi < 2; ++mi)
        #pragma unroll
        for (int i = 0; i < 8; ++i) acc[mi][i] = zero;

    G2_STAGE(0, 0);
    for (int kt = 0; kt < 4; ++kt) {
        int cur = kt & 1;
        if (kt < 3) G2_STAGE(cur ^ 1, kt + 1);
        __syncthreads();
        int4v a[2];
        #pragma unroll
        for (int mi = 0; mi < 2; ++mi)
            a[mi] = *(const int4v*)&lA[cur][(((mi << 4) + r) << 6) + ((q ^ (r & 3)) << 4)];
        #pragma unroll
        for (int i = 0; i < 8; ++i) {
            int n = (w << 7) + (i << 4) + r;
            int sb = (q << 9) + (n ^ ((q & 1) << 3));
            int4v bb = *(const int4v*)&lB[cur][sb << 4];
            acc[0][i] = __builtin_amdgcn_mfma_i32_16x16x64_i8(a[0], bb, acc[0][i], 0, 0, 0);
            acc[1][i] = __builtin_amdgcn_mfma_i32_16x16x64_i8(a[1], bb, acc[1][i], 0, 0, 0);
        }
        __syncthreads();
    }
    #undef G2_STAGE

    float ds[8];
    #pragma unroll
    for (int i = 0; i < 8; ++i)
        ds[i] = dsc[e * HD + (nh << 9) + (w << 7) + (i << 4) + r];
    float isr[2][4]; int tok[2][4];
    #pragma unroll
    for (int mi = 0; mi < 2; ++mi)
        #pragma unroll
        for (int g = 0; g < 4; ++g) {
            int slot = m0 + mi * 16 + q * 4 + g;
            isr[mi][g] = isc[slot];
            tok[mi][g] = perm[slot];
        }
    #pragma unroll
    for (int mi = 0; mi < 2; ++mi)
        #pragma unroll
        for (int g = 0; g < 4; ++g) {
            int slot = m0 + mi * 16 + q * 4 + g;
            if (slot < gend) {
                float vs = isr[mi][g];
                size_t ob = (size_t)tok[mi][g] * HD + (nh << 9) + (w << 7) + r;
                #pragma unroll
                for (int i = 0; i < 8; ++i)
                    out[ob + (i << 4)] = (float)acc[mi][i][g] * vs * ds[i];
            }
        }
}

extern "C" void kernel_launch(void* const* d_in, const int* in_sizes, int n_in,
                              void* d_out, int out_size, void* d_ws, size_t ws_size,
                              hipStream_t stream) {
    const float* hidden = (const float*)d_in[0];
    const int*   ids    = (const int*)d_in[1];
    const int*   gq     = (const int*)d_in[2];
    const float* gsc    = (const float*)d_in[3];
    const int*   uq     = (const int*)d_in[4];
    const float* usc    = (const float*)d_in[5];
    const int*   dq     = (const int*)d_in[6];
    const float* dsc    = (const float*)d_in[7];
    const int*   t2e    = (const int*)d_in[8];
    float* out = (float*)d_out;

    char* ws = (char*)d_ws;
    signed char* xq  = (signed char*)(ws + XQ_OFF);
    signed char* iq  = (signed char*)(ws + IQ_OFF);
    signed char* pb1 = (signed char*)(ws + PB1_OFF);
    signed char* pb2 = (signed char*)(ws + PB2_OFF);
    int*   perm = (int*)(ws + PERM_OFF);
    float* xs   = (float*)(ws + XS_OFF);
    float* isc  = (float*)(ws + IS_OFF);
    int*   meta = (int*)(ws + META_OFF);
    int*   bc   = (int*)(ws + BC_OFF);
    int*   bbase= (int*)(ws + BB_OFF);

    k_hist<<<64, 256, 0, stream>>>(ids, t2e, bc);
    k_scan<<<1, 512, 0, stream>>>(bc, bbase, meta);
    k_assign<<<64, 256, 0, stream>>>(ids, t2e, bbase, perm);
    k_repack<<<1536, 256, 0, stream>>>(gq, uq, dq, pb1, pb2);
    k_quant<<<4096, 256, 0, stream>>>(hidden, perm, xq, xs);
    k_gemm1<<<264, 256, 0, stream>>>(xq, pb1, xs, gsc, usc, meta, iq, isc);
    k_gemm2<<<1040, 256, 0, stream>>>(iq, pb2, isc, dsc, meta, perm, out);
}